// Round 1
// baseline (31.991 us; speedup 1.0000x reference)
//
#include <hip/hip_runtime.h>

// DistanceInfoNCE, algebraically reduced:
//   S[i] = B*sq[i] + sum_sq - 2*dot(a_i, asum) + neg_dist[i]
// avoids the B x B gram matrix entirely (O(B*D) instead of O(B^2*D)).
//
// ws layout (floats):
//   [0]        loss_sum
//   [1]        sum_sq
//   [4..259]   asum[256]        (16B aligned for float4)
//   [260..]    sq[B]
//   [260+B..]  pos_dist[B]
//   [260+2B..] neg_dist[B]

#define BLK 256
#define NBLOCKS 256
#define NWAVES (NBLOCKS * (BLK / 64))   // 1024 waves

__device__ __forceinline__ float wave_reduce(float v) {
    #pragma unroll
    for (int off = 32; off > 0; off >>= 1) v += __shfl_down(v, off, 64);
    return v;
}

__global__ void k_init(float* __restrict__ ws) {
    for (int i = threadIdx.x; i < 260; i += BLK) ws[i] = 0.0f;
}

__global__ void k_pass1(const float4* __restrict__ A, const float4* __restrict__ P,
                        const float4* __restrict__ N, float* __restrict__ ws, int B) {
    const int lane = threadIdx.x & 63;
    const int wid  = threadIdx.x >> 6;
    const int gwave = blockIdx.x * (BLK / 64) + wid;

    float* __restrict__ sq_o = ws + 260;
    float* __restrict__ pd_o = ws + 260 + B;
    float* __restrict__ nd_o = ws + 260 + 2 * B;

    __shared__ float lsum[256];   // block-level column accumulator
    __shared__ float sqred[4];
    lsum[threadIdx.x] = 0.0f;
    __syncthreads();

    float4 col = make_float4(0.f, 0.f, 0.f, 0.f);
    float wave_sq = 0.0f;

    for (int i = gwave; i < B; i += NWAVES) {
        const float4 a = A[i * 64 + lane];
        const float4 p = P[i * 64 + lane];
        const float4 n = N[i * 64 + lane];
        col.x += a.x; col.y += a.y; col.z += a.z; col.w += a.w;
        const float dpx = a.x - p.x, dpy = a.y - p.y, dpz = a.z - p.z, dpw = a.w - p.w;
        const float dnx = a.x - n.x, dny = a.y - n.y, dnz = a.z - n.z, dnw = a.w - n.w;
        float s_sq = a.x * a.x + a.y * a.y + a.z * a.z + a.w * a.w;
        float s_pd = dpx * dpx + dpy * dpy + dpz * dpz + dpw * dpw;
        float s_nd = dnx * dnx + dny * dny + dnz * dnz + dnw * dnw;
        #pragma unroll
        for (int off = 32; off > 0; off >>= 1) {
            s_sq += __shfl_down(s_sq, off, 64);
            s_pd += __shfl_down(s_pd, off, 64);
            s_nd += __shfl_down(s_nd, off, 64);
        }
        if (lane == 0) {
            sq_o[i] = s_sq;
            pd_o[i] = s_pd;
            nd_o[i] = s_nd;
            wave_sq += s_sq;
        }
    }

    // per-block column reduction in LDS (4 waves collide -> LDS atomics, cheap)
    atomicAdd(&lsum[4 * lane + 0], col.x);
    atomicAdd(&lsum[4 * lane + 1], col.y);
    atomicAdd(&lsum[4 * lane + 2], col.z);
    atomicAdd(&lsum[4 * lane + 3], col.w);
    if (lane == 0) sqred[wid] = wave_sq;
    __syncthreads();

    atomicAdd(&ws[4 + threadIdx.x], lsum[threadIdx.x]);   // one global atomic/col/block
    if (threadIdx.x == 0)
        atomicAdd(&ws[1], sqred[0] + sqred[1] + sqred[2] + sqred[3]);
}

__global__ void k_pass2(const float4* __restrict__ A, float* __restrict__ ws, int B) {
    const int lane = threadIdx.x & 63;
    const int wid  = threadIdx.x >> 6;
    const int gwave = blockIdx.x * (BLK / 64) + wid;

    const float* __restrict__ sq_i = ws + 260;
    const float* __restrict__ pd_i = ws + 260 + B;
    const float* __restrict__ nd_i = ws + 260 + 2 * B;

    const float sum_sq = ws[1];
    const float4 s = ((const float4*)(ws + 4))[lane];   // asum fragment, hoisted
    const float Bf = (float)B;

    float wave_loss = 0.0f;
    for (int i = gwave; i < B; i += NWAVES) {
        const float4 a = A[i * 64 + lane];
        float d = a.x * s.x + a.y * s.y + a.z * s.z + a.w * s.w;
        d = wave_reduce(d);
        if (lane == 0) {
            const float S = Bf * sq_i[i] + sum_sq - 2.0f * d + nd_i[i];
            const float pos_sim = expf(-2.0f * pd_i[i]);   // /TAU, TAU=0.5
            const float neg_sim = expf(-2.0f * S);
            const float loss = -logf(pos_sim / (pos_sim + neg_sim + 1e-9f));
            wave_loss += loss;
        }
    }

    __shared__ float lred[4];
    if (lane == 0) lred[wid] = wave_loss;
    __syncthreads();
    if (threadIdx.x == 0)
        atomicAdd(&ws[0], lred[0] + lred[1] + lred[2] + lred[3]);
}

__global__ void k_fin(const float* __restrict__ ws, float* __restrict__ out, float invB) {
    out[0] = ws[0] * invB;   // invB = 1/4096 is a power of 2: exact, == mean
}

extern "C" void kernel_launch(void* const* d_in, const int* in_sizes, int n_in,
                              void* d_out, int out_size, void* d_ws, size_t ws_size,
                              hipStream_t stream) {
    const float4* A = (const float4*)d_in[0];
    const float4* P = (const float4*)d_in[1];
    const float4* N = (const float4*)d_in[2];
    float* ws = (float*)d_ws;
    float* out = (float*)d_out;
    const int D = 256;
    const int B = in_sizes[0] / D;   // 4096

    k_init <<<1, BLK, 0, stream>>>(ws);
    k_pass1<<<NBLOCKS, BLK, 0, stream>>>(A, P, N, ws, B);
    k_pass2<<<NBLOCKS, BLK, 0, stream>>>(A, ws, B);
    k_fin  <<<1, 1, 0, stream>>>(ws, out, 1.0f / (float)B);
}